// Round 6
// baseline (321.817 us; speedup 1.0000x reference)
//
#include <hip/hip_runtime.h>
#include <stdint.h>

typedef unsigned short ushort_t;
typedef __attribute__((ext_vector_type(8))) short bf16x8;   // 8 bf16 = 4 VGPRs (MFMA A/B frag)
typedef __attribute__((ext_vector_type(4))) float f32x4;    // MFMA C/D frag / fp32 vec-load

#define BM 256
#define BN 256
#define BK 64
#define SCALING 2.0f

static __device__ __forceinline__ unsigned short f2b(float f) {
    union { float f; unsigned int i; } v;
    v.f = f;
    unsigned int r = 0x7FFFu + ((v.i >> 16) & 1u);   // round-to-nearest-even
    return (unsigned short)((v.i + r) >> 16);
}

// async global->LDS, 16 bytes/lane. HW dest = wave-uniform base + lane*16.
static __device__ __forceinline__ void ld_g2l16(const void* g, void* l) {
    __builtin_amdgcn_global_load_lds(
        (const __attribute__((address_space(1))) void*)g,
        (__attribute__((address_space(3))) void*)l,
        16, 0, 0);
}

#define SFENCE()     __builtin_amdgcn_sched_barrier(0)
#define BARRIER()    do { SFENCE(); __builtin_amdgcn_s_barrier(); SFENCE(); } while (0)
#define WAIT_LGKM0() do { asm volatile("s_waitcnt lgkmcnt(0)" ::: "memory"); SFENCE(); } while (0)
#define WAIT_VM(N)   do { asm volatile("s_waitcnt vmcnt(" #N ")" ::: "memory"); SFENCE(); } while (0)

// ---------------------------------------------------------------------------
// Kernel 1: W_eff[o][d] = W[o][d] + SCALING * sum_r B[o][r]*A[r][d]  (fp32 in, bf16 out RNE)
// ---------------------------------------------------------------------------
__global__ void weff_kernel(const float* __restrict__ W,
                            const float* __restrict__ A,
                            const float* __restrict__ Bm,
                            ushort_t* __restrict__ Weff,
                            int D, int R) {
    int gid = blockIdx.x * blockDim.x + threadIdx.x;
    int perRow = D >> 3;
    if (gid >= D * perRow) return;
    int o  = gid / perRow;
    int d0 = (gid - o * perRow) << 3;

    float br[16];
    for (int r = 0; r < R; ++r) br[r] = SCALING * Bm[(size_t)o * R + r];

    float acc[8];
    #pragma unroll
    for (int j = 0; j < 8; ++j) acc[j] = W[(size_t)o * D + d0 + j];
    for (int r = 0; r < R; ++r) {
        #pragma unroll
        for (int j = 0; j < 8; ++j) acc[j] += br[r] * A[(size_t)r * D + d0 + j];
    }
    union { bf16x8 v; unsigned short s[8]; } ov;
    #pragma unroll
    for (int j = 0; j < 8; ++j) ov.s[j] = f2b(acc[j]);
    *(bf16x8*)(Weff + (size_t)o * D + d0) = ov.v;
}

// ---------------------------------------------------------------------------
// Kernel 2: x fp32 -> bf16 RNE (8 elems/thread)  [~35us @ 5.7 TB/s -- near BW]
// ---------------------------------------------------------------------------
__global__ void cvt_x_kernel(const float* __restrict__ x, ushort_t* __restrict__ xb, long n) {
    long gid = (long)(blockIdx.x * blockDim.x + threadIdx.x) * 8;
    if (gid >= n) return;
    f32x4 a = *(const f32x4*)(x + gid);
    f32x4 b = *(const f32x4*)(x + gid + 4);
    union { bf16x8 v; unsigned short s[8]; } ov;
    ov.s[0] = f2b(a[0]); ov.s[1] = f2b(a[1]); ov.s[2] = f2b(a[2]); ov.s[3] = f2b(a[3]);
    ov.s[4] = f2b(b[0]); ov.s[5] = f2b(b[1]); ov.s[6] = f2b(b[2]); ov.s[7] = f2b(b[3]);
    *(bf16x8*)(xb + gid) = ov.v;
}

// ---------------------------------------------------------------------------
// Kernel 3: Y[m][n] = sum_k X[m][k]*Wt[n][k] + bias[n]  (bf16 X/Wt, fp32 bias/out)
//   m201-style 4-phase-per-K-tile lockstep on the proven 256x256/BK=64/8-wave
//   geometry, all staging via global_load_lds (reg-staging abandoned: m151 +
//   R3/R4/R5 all measured it slower).
//
//   Phases (rh = wave-row-half, ks = K-half of BK):
//     P1 (rh0,ks0): stage Ah0(t+1); VM(2)|VM(0); BAR; read bF0(4)+aF(4);
//                   lgkm0; 16 MFMA; BAR
//     P2 (rh1,ks0): read aF(4); stage Ah1(t+1); BAR; lgkm0; 16 MFMA; BAR
//     P3 (rh0,ks1): read bF1(4)+aF(4); stage Bh0(t+1); BAR; lgkm0; 16 MFMA; BAR
//     P4 (rh1,ks1): read aF(4); stage Bh1(t+1); BAR; lgkm0; 16 MFMA; BAR
//
//   Staging targets buf[(t+1)&1], which held tile t-1 and is entirely free
//   (last reads completed before tile t-1's final barrier).
//   vmcnt ledger (2 loads per stage op, FIFO):
//     at P1(t): pending = tile t's 8 (staged P1..P4 of t-1) + 2 just issued
//     -> WAIT_VM(2) retires exactly tile t's 8.  Never 0 in steady state.
//   Latency gaps to first read: Ah0 4 phases, Ah1 3 (HBM ~900cy OK);
//   Bh0 2, Bh1 1 phase (Weff 2MB = L2-resident, ~250cy OK -- B staged LAST).
//   P1's ds_reads sit AFTER the vm-wait+barrier (their data lands there);
//   P2-P4's sit before their barrier (data landed since P1).
// ---------------------------------------------------------------------------
template<int IB>
static __device__ __forceinline__ void mfma16(const bf16x8 (&aF)[4], const bf16x8 (&bF)[4],
                                              f32x4 (&acc)[8][4]) {
    __builtin_amdgcn_s_setprio(1);
    #pragma unroll
    for (int i = 0; i < 4; ++i)
        #pragma unroll
        for (int j = 0; j < 4; ++j)
            acc[IB + i][j] = __builtin_amdgcn_mfma_f32_16x16x32_bf16(aF[i], bF[j], acc[IB + i][j], 0, 0, 0);
    __builtin_amdgcn_s_setprio(0);
}

__global__ __launch_bounds__(512, 2) void gemm_bt_bias(
    const ushort_t* __restrict__ X,     // [M,K] bf16
    const ushort_t* __restrict__ Wt,    // [N,K] bf16 (Weff)
    const float*    __restrict__ bias,  // [N]   fp32
    float*          __restrict__ Y,     // [M,N] fp32
    int M, int N, int K)
{
    __shared__ __align__(16) ushort_t sA[2][BM * BK];   // 2 x 32 KB
    __shared__ __align__(16) ushort_t sB[2][BN * BK];   // 2 x 32 KB

    const int tid  = threadIdx.x;
    const int lane = tid & 63;
    const int wave = tid >> 6;
    const int wm   = wave >> 2;          // 0..1  -> rows [wm*128, +128)
    const int wn   = wave & 3;           // 0..3  -> cols [wn*64,  +64)

    // ---- XCD-aware tile assignment ----
    const int nT = N / BN;
    const int mT = M / BM;
    int mTile, nTile;
    if (((mT * nT) & 7) == 0 && (((mT * nT) >> 3) % nT) == 0) {
        const int xcd = blockIdx.x & 7;
        const int loc = blockIdx.x >> 3;
        const int mPerXcd = ((mT * nT) >> 3) / nT;
        mTile = xcd * mPerXcd + loc / nT;
        nTile = loc % nT;
    } else {
        nTile = blockIdx.x % nT;
        mTile = blockIdx.x / nT;
    }
    const int mBase = mTile * BM;
    const int nBase = nTile * BN;

    // ---- staging map: thread tid owns cell (row = tid>>3 + q*64, slot = tid&7);
    //      slot s of row r holds chunk s^(r&7)  (r&7 invariant under +64)
    const int sRow   = tid >> 3;
    const int sChunk = (tid & 7) ^ (sRow & 7);
    const ushort_t* gA = X  + (size_t)(mBase + sRow) * K + sChunk * 8;
    const ushort_t* gB = Wt + (size_t)(nBase + sRow) * K + sChunk * 8;

    // ---- fragment read addressing (row&7 == lane&7 for every fragment row) ----
    const int fRow  = lane & 15;
    const int g     = lane >> 4;
    const int aBase = (wm * 128 + fRow) * BK;
    const int bBase = (wn * 64  + fRow) * BK;
    const int s0    = ((0 + g) ^ (lane & 7)) * 8;
    const int s1    = ((4 + g) ^ (lane & 7)) * 8;

    f32x4 acc[8][4];
    #pragma unroll
    for (int i = 0; i < 8; ++i)
        #pragma unroll
        for (int j = 0; j < 4; ++j)
            acc[i][j] = (f32x4){0.f, 0.f, 0.f, 0.f};

    const int nt = K / BK;

    // ---- prologue: stage tile 0 fully (8 loads in flight) ----
    {
        ushort_t* lA0 = &sA[0][0] + tid * 8;
        ushort_t* lB0 = &sB[0][0] + tid * 8;
        #pragma unroll
        for (int q = 0; q < 4; ++q) ld_g2l16(gA + (size_t)(q * 64) * K, lA0 + q * 4096);
        #pragma unroll
        for (int q = 0; q < 4; ++q) ld_g2l16(gB + (size_t)(q * 64) * K, lB0 + q * 4096);
    }

    for (int t = 0; t < nt; ++t) {
        const ushort_t* pA = &sA[t & 1][0];
        const ushort_t* pB = &sB[t & 1][0];
        const bool st = (t + 1 < nt);
        ushort_t* dA = &sA[(t + 1) & 1][0] + tid * 8;
        ushort_t* dB = &sB[(t + 1) & 1][0] + tid * 8;
        const ushort_t* gAt = gA + (size_t)(t + 1) * BK;
        const ushort_t* gBt = gB + (size_t)(t + 1) * BK;

        bf16x8 aF[4], bF[4];

        // ================= P1: (rh0, ks0) =================
        if (st) {
            ld_g2l16(gAt + (size_t)(0 * 64) * K, dA + 0 * 4096);
            ld_g2l16(gAt + (size_t)(1 * 64) * K, dA + 1 * 4096);
            WAIT_VM(2);          // retire tile t's 8 loads; the 2 just issued fly
        } else {
            WAIT_VM(0);          // last tile: full drain (once)
        }
        BARRIER();               // tile t landed CU-wide
        #pragma unroll
        for (int j = 0; j < 4; ++j) bF[j] = *(const bf16x8*)(pB + bBase + j * (16 * BK) + s0);
        #pragma unroll
        for (int i = 0; i < 4; ++i) aF[i] = *(const bf16x8*)(pA + aBase + i * (16 * BK) + s0);
        WAIT_LGKM0();
        mfma16<0>(aF, bF, acc);
        BARRIER();

        // ================= P2: (rh1, ks0) =================
        #pragma unroll
        for (int i = 0; i < 4; ++i) aF[i] = *(const bf16x8*)(pA + aBase + (4 + i) * (16 * BK) + s0);
        if (st) {
            ld_g2l16(gAt + (size_t)(2 * 64) * K, dA + 2 * 4096);
            ld_g2l16(gAt + (size_t)(3 * 64) * K, dA + 3 * 4096);
        }
        BARRIER();
        WAIT_LGKM0();
        mfma16<4>(aF, bF, acc);              // bF reuse (ks0)
        BARRIER();

        // ================= P3: (rh0, ks1) =================
        #pragma unroll
        for (int j = 0; j < 4; ++j) bF[j] = *(const bf16x8*)(pB + bBase + j * (16 * BK) + s1);
        #pragma unroll
        for (int i = 0; i < 4; ++i) aF[i] = *(const bf16x8*)(pA + aBase + i * (16 * BK) + s1);
        if (st) {
            ld_g2l16(gBt + (size_t)(0 * 64) * K, dB + 0 * 4096);
            ld_g2l16(gBt + (size_t)(1 * 64) * K, dB + 1 * 4096);
        }
        BARRIER();
        WAIT_LGKM0();
        mfma16<0>(aF, bF, acc);
        BARRIER();

        // ================= P4: (rh1, ks1) =================
        #pragma unroll
        for (int i = 0; i < 4; ++i) aF[i] = *(const bf16x8*)(pA + aBase + (4 + i) * (16 * BK) + s1);
        if (st) {
            ld_g2l16(gBt + (size_t)(2 * 64) * K, dB + 2 * 4096);
            ld_g2l16(gBt + (size_t)(3 * 64) * K, dB + 3 * 4096);
        }
        BARRIER();
        WAIT_LGKM0();
        mfma16<4>(aF, bF, acc);              // bF reuse (ks1)
        BARRIER();
    }

    // ---- epilogue: C/D layout col(n)=lane&15, row(m)=(lane>>4)*4+reg ----
    const int col  = lane & 15;
    const int rowq = (lane >> 4) * 4;
    #pragma unroll
    for (int j = 0; j < 4; ++j) {
        const int n    = nBase + wn * 64 + j * 16 + col;
        const float bv = bias[n];
        #pragma unroll
        for (int i = 0; i < 8; ++i) {
            const int mRow = mBase + wm * 128 + i * 16 + rowq;
            #pragma unroll
            for (int r = 0; r < 4; ++r)
                Y[(size_t)(mRow + r) * N + n] = acc[i][j][r] + bv;
        }
    }
}

// ---------------------------------------------------------------------------
// Fallback (only if ws too small / shapes odd): correct fused fp32 kernel.
// ---------------------------------------------------------------------------
__global__ __launch_bounds__(256) void fused_naive(
    const float* __restrict__ x, const float* __restrict__ W,
    const float* __restrict__ b, const float* __restrict__ A,
    const float* __restrict__ Bm, float* __restrict__ y, int D, int R)
{
    extern __shared__ float smem[];
    float* sx  = smem;
    float* red = smem + D;
    float* sh  = red + 256;
    const int tid = threadIdx.x;
    const int m   = blockIdx.x;

    for (int i = tid; i < D; i += 256) sx[i] = x[(size_t)m * D + i];
    __syncthreads();

    for (int r = 0; r < R; ++r) {
        float p = 0.f;
        for (int k = tid; k < D; k += 256) p += sx[k] * A[(size_t)r * D + k];
        red[tid] = p; __syncthreads();
        for (int s = 128; s > 0; s >>= 1) {
            if (tid < s) red[tid] += red[tid + s];
            __syncthreads();
        }
        if (tid == 0) sh[r] = red[0];
        __syncthreads();
    }

    for (int n = tid; n < D; n += 256) {
        float base = 0.f;
        const float* wr = W + (size_t)n * D;
        for (int k = 0; k < D; ++k) base += sx[k] * wr[k];
        float lora = 0.f;
        for (int r = 0; r < R; ++r) lora += sh[r] * Bm[(size_t)n * R + r];
        y[(size_t)m * D + n] = base + b[n] + SCALING * lora;
    }
}

extern "C" void kernel_launch(void* const* d_in, const int* in_sizes, int n_in,
                              void* d_out, int out_size, void* d_ws, size_t ws_size,
                              hipStream_t stream) {
    const float* x  = (const float*)d_in[0];
    const float* W  = (const float*)d_in[1];
    const float* b  = (const float*)d_in[2];
    const float* A  = (const float*)d_in[3];
    const float* Bm = (const float*)d_in[4];
    float* y = (float*)d_out;

    const int D = in_sizes[2];                 // 1024
    const int R = in_sizes[3] / D;             // 8
    const int M = in_sizes[0] / D;             // 32768
    const long xN = (long)M * D;
    (void)n_in; (void)out_size;

    const size_t weffBytes = (size_t)D * D * sizeof(ushort_t);   // 2 MB
    const size_t xbBytes   = (size_t)xN * sizeof(ushort_t);      // 67 MB

    if (ws_size >= weffBytes + xbBytes &&
        (D % BN) == 0 && (M % BM) == 0 && (D % BK) == 0) {
        ushort_t* Weff = (ushort_t*)d_ws;
        ushort_t* xb   = (ushort_t*)((char*)d_ws + weffBytes);

        int wthreads = D * (D / 8);
        weff_kernel<<<dim3((wthreads + 255) / 256), 256, 0, stream>>>(W, A, Bm, Weff, D, R);

        long cthreads = xN / 8;
        cvt_x_kernel<<<dim3((unsigned)((cthreads + 255) / 256)), 256, 0, stream>>>(x, xb, xN);

        dim3 grid((M / BM) * (D / BN));        // 1D; kernel does XCD-aware remap
        gemm_bt_bias<<<grid, 512, 0, stream>>>(xb, Weff, b, y, M, D, D);
    } else {
        size_t shmem = (size_t)(D + 256 + R) * sizeof(float);
        fused_naive<<<dim3(M), 256, shmem, stream>>>(x, W, b, A, Bm, y, D, R);
    }
}